// Round 1
// baseline (3498.606 us; speedup 1.0000x reference)
//
#include <hip/hip_runtime.h>
#include <math.h>

// Problem constants
#define B_    256
#define K_    64
#define D_    256
#define T_    8
#define NROW  (B_*K_)        // 16384 rows of the big GEMMs

// ---------- device helpers ----------
__device__ __forceinline__ float sigmoid_f(float x) { return 1.f / (1.f + expf(-x)); }
__device__ __forceinline__ float gelu_f(float x) {
  return 0.5f * x * (1.f + erff(x * 0.70710678118654752440f));
}
// reference _mu_s with a2<b2 guaranteed by caller
__device__ __forceinline__ float muS_f(float x, float a2, float b2) {
  float mid = 0.5f * (a2 + b2);
  float inv = 1.f / (b2 - a2 + 1e-12f);
  if (x > b2)  return 1.f;
  if (x > mid) { float u = (b2 - x) * inv; return 1.f - 2.f * u * u; }
  if (x > a2)  { float u = (x - a2) * inv; return 2.f * u * u; }
  return 0.f;
}
// defuzzify one (rb, rs) pair -> 0.5*cen_b + 0.5*cen_s
__device__ __forceinline__ float defuzz_one(float rb_, float rs_, float ab, float bb) {
  float e2b = 2.f * bb;
  float cb = 4.f * tanhf(rb_);
  float num = 0.f, den = 0.f;
  #pragma unroll
  for (int j = 0; j < 41; ++j) {
    float gj = -4.f + 0.2f * (float)j;
    float mu = 1.f / (1.f + powf(fabsf((gj - cb) / ab), e2b));
    num += gj * mu; den += mu;
  }
  float cenb = num / (den + 1e-12f);
  float cs = 4.f * tanhf(rs_);
  float as_ = fminf(fmaxf(cs - 1.f, -4.f), 4.f);
  float bs_ = fminf(fmaxf(cs + 1.f, -4.f), 4.f);
  num = 0.f; den = 0.f;
  {
    float mid = 0.5f * (as_ + bs_);
    float inv = 1.f / (bs_ - as_ + 1e-12f);
    #pragma unroll
    for (int j = 0; j < 41; ++j) {
      float gj = -4.f + 0.2f * (float)j;
      float mu;
      if (gj > bs_)      mu = 1.f;
      else if (gj > mid) { float u = (bs_ - gj) * inv; mu = 1.f - 2.f * u * u; }
      else if (gj > as_) { float u = (gj - as_) * inv; mu = 2.f * u * u; }
      else               mu = 0.f;
      num += gj * mu; den += mu;
    }
  }
  float cens = num / (den + 1e-12f);
  return 0.5f * cenb + 0.5f * cens;
}

// ---------- kernel 0: one-time precompute ----------
// lr = wsi@W_lr+b_lr ; g = gen@W_g+b_g ; fuzzify ; QI/QG ; qIp = QI@WkI^T, qGp = QG@WkG^T
__global__ __launch_bounds__(256) void precompute_kernel(
    const float* __restrict__ wsi, const float* __restrict__ gen,
    const float* __restrict__ W_lr, const float* __restrict__ b_lr,
    const float* __restrict__ W_g,  const float* __restrict__ b_g,
    const float* __restrict__ WqI,  const float* __restrict__ WqG,
    const float* __restrict__ WkI,  const float* __restrict__ WkG,
    const float* __restrict__ a_p,  const float* __restrict__ b_p,
    float* __restrict__ qIp, float* __restrict__ qGp)
{
  int b = blockIdx.x, t = threadIdx.x;
  __shared__ float xrow[1024];
  __shared__ float fz[512];
  __shared__ float Q[256];
  float ab = fmaxf(a_p[0], 0.001f), bb = fmaxf(b_p[0], 0.001f);
  float e2b = 2.f * bb;

  // ----- I path -----
  for (int i = t; i < 1024; i += 256) xrow[i] = wsi[(size_t)b*1024 + i];
  __syncthreads();
  float acc = b_lr[t];
  for (int e = 0; e < 1024; ++e) acc = fmaf(xrow[e], W_lr[(size_t)e*256 + t], acc);
  {
    float xs = 4.f * tanhf(acc * 0.25f);
    fz[t]       = 1.f / (1.f + powf(fabsf(xs / ab), e2b));
    fz[256 + t] = muS_f(xs, -1.f, 1.f);
  }
  __syncthreads();
  float qi = 0.f;
  for (int e = 0; e < 512; ++e) qi = fmaf(fz[e], WqI[(size_t)e*256 + t], qi);
  Q[t] = qi;
  __syncthreads();
  float qp = 0.f;
  for (int dd = 0; dd < 256; ++dd) qp = fmaf(WkI[(size_t)t*256 + dd], Q[dd], qp);
  qIp[(size_t)b*256 + t] = qp;
  __syncthreads();

  // ----- G path -----
  for (int i = t; i < 512; i += 256) xrow[i] = gen[(size_t)b*512 + i];
  __syncthreads();
  acc = b_g[t];
  for (int e = 0; e < 512; ++e) acc = fmaf(xrow[e], W_g[(size_t)e*256 + t], acc);
  {
    float xs = 4.f * tanhf(acc * 0.25f);
    fz[t]       = 1.f / (1.f + powf(fabsf(xs / ab), e2b));
    fz[256 + t] = muS_f(xs, -1.f, 1.f);
  }
  __syncthreads();
  qi = 0.f;
  for (int e = 0; e < 512; ++e) qi = fmaf(fz[e], WqG[(size_t)e*256 + t], qi);
  Q[t] = qi;
  __syncthreads();
  qp = 0.f;
  for (int dd = 0; dd < 256; ++dd) qp = fmaf(WkG[(size_t)t*256 + dd], Q[dd], qp);
  qGp[(size_t)b*256 + t] = qp;
}

// ---------- kernel 1 (per step): attention + defuzz + small row-GEMMs ----------
// one block per batch b; produces r[b,:], rW1[b,:], rWf[b,:], rWi[b,:]
__global__ __launch_bounds__(256) void step_attn_kernel(
    const float* __restrict__ Fcur, const float* __restrict__ FT, int bcast,
    const float* __restrict__ qIp, const float* __restrict__ qGp,
    const float* __restrict__ WvI, const float* __restrict__ WvG,
    const float* __restrict__ W1,  const float* __restrict__ Wf, const float* __restrict__ Wi,
    const float* __restrict__ a_p, const float* __restrict__ b_p,
    float* __restrict__ r_out, float* __restrict__ rW1_out,
    float* __restrict__ rWf_out, float* __restrict__ rWi_out)
{
  int b = blockIdx.x, t = threadIdx.x;
  __shared__ float qv[2][256];
  __shared__ float red[2][256];
  __shared__ float p[2][64];
  __shared__ float ftbar[2][256];
  __shared__ float rt[2][512];
  __shared__ float rL[256];
  const float* Fb = bcast ? FT : (Fcur + (size_t)b * K_ * D_);

  qv[0][t] = qIp[(size_t)b*256 + t];
  qv[1][t] = qGp[(size_t)b*256 + t];
  __syncthreads();

  // scores: sI[k] = Ft[b,k,:] . qIp[b,:] / 16 (4 partial lanes per k)
  {
    int k = t & 63, part = t >> 6;
    const float* frow = Fb + (size_t)k * D_ + part * 64;
    const float* q0 = &qv[0][part * 64];
    const float* q1 = &qv[1][part * 64];
    float s0 = 0.f, s1 = 0.f;
    for (int d = 0; d < 64; ++d) { float fv = frow[d]; s0 = fmaf(fv, q0[d], s0); s1 = fmaf(fv, q1[d], s1); }
    red[0][t] = s0; red[1][t] = s1;
  }
  __syncthreads();
  // softmax over K=64 (wave 0 -> I, wave 1 -> G)
  if (t < 128) {
    int which = t >> 6, kk = t & 63;
    float s = (red[which][kk] + red[which][64+kk] + red[which][128+kk] + red[which][192+kk]) * (1.f/16.f);
    float m = s;
    for (int off = 32; off; off >>= 1) m = fmaxf(m, __shfl_xor(m, off, 64));
    float e = expf(s - m);
    float sum = e;
    for (int off = 32; off; off >>= 1) sum += __shfl_xor(sum, off, 64);
    p[which][kk] = e / sum;
  }
  __syncthreads();
  // ftbar[d] = sum_k p[k] * Ft[b,k,d]   (coalesced across threads)
  {
    float f0 = 0.f, f1 = 0.f;
    for (int kk = 0; kk < 64; ++kk) {
      float fv = Fb[(size_t)kk * D_ + t];
      f0 = fmaf(p[0][kk], fv, f0); f1 = fmaf(p[1][kk], fv, f1);
    }
    ftbar[0][t] = f0; ftbar[1][t] = f1;
  }
  __syncthreads();
  // rt = ftbar @ Wv  (512 outputs each for I and G)
  {
    float aI0=0.f, aI1=0.f, aG0=0.f, aG1=0.f;
    for (int d = 0; d < 256; ++d) {
      float fI = ftbar[0][d], fG = ftbar[1][d];
      const float* wI = WvI + (size_t)d * 512;
      const float* wG = WvG + (size_t)d * 512;
      aI0 = fmaf(fI, wI[t], aI0);       aI1 = fmaf(fI, wI[t+256], aI1);
      aG0 = fmaf(fG, wG[t], aG0);       aG1 = fmaf(fG, wG[t+256], aG1);
    }
    rt[0][t] = aI0; rt[0][t+256] = aI1; rt[1][t] = aG0; rt[1][t+256] = aG1;
  }
  __syncthreads();
  // r = 0.5*defuzz(rtI) + 0.5*defuzz(rtG)
  {
    float ab = fmaxf(a_p[0], 0.001f), bb = fmaxf(b_p[0], 0.001f);
    float rI = defuzz_one(rt[0][t], rt[0][256+t], ab, bb);
    float rG = defuzz_one(rt[1][t], rt[1][256+t], ab, bb);
    float rv = 0.5f * rI + 0.5f * rG;
    rL[t] = rv;
    r_out[(size_t)b*256 + t] = rv;
  }
  __syncthreads();
  // rW1 = r@mlp_W1, rWf = r@Wf, rWi = r@Wi
  {
    float w0=0.f, w1=0.f, wf=0.f, wi=0.f;
    for (int d = 0; d < 256; ++d) {
      float rv = rL[d];
      w0 = fmaf(rv, W1[(size_t)d*512 + t],       w0);
      w1 = fmaf(rv, W1[(size_t)d*512 + t + 256], w1);
      wf = fmaf(rv, Wf[(size_t)d*256 + t],       wf);
      wi = fmaf(rv, Wi[(size_t)d*256 + t],       wi);
    }
    rW1_out[(size_t)b*512 + t]       = w0;
    rW1_out[(size_t)b*512 + t + 256] = w1;
    rWf_out[(size_t)b*256 + t] = wf;
    rWi_out[(size_t)b*256 + t] = wi;
  }
}

// ---------- kernel 2 (per step): U = Ft @ [mlp_W1 | Vf | Vi]  (16384x256 @ 256x1024) ----------
__global__ __launch_bounds__(256) void gemm1_kernel(
    const float* __restrict__ Fcur, const float* __restrict__ FT, int bcast,
    const float* __restrict__ W1, const float* __restrict__ Vf, const float* __restrict__ Vi,
    float* __restrict__ U)
{
  int bx = blockIdx.x & 15;   // 16 n-tiles of 64 over N=1024
  int by = blockIdx.x >> 4;   // 256 m-tiles of 64
  int n0 = bx * 64, m0 = by * 64;
  const float* Bp; int ldb, nb;
  if (n0 < 512)      { Bp = W1; ldb = 512; nb = n0; }
  else if (n0 < 768) { Bp = Vf; ldb = 256; nb = n0 - 512; }
  else               { Bp = Vi; ldb = 256; nb = n0 - 768; }
  __shared__ float As[16][64];
  __shared__ float Bs[16][64];
  int tid = threadIdx.x, tx = tid & 15, ty = tid >> 4;
  float acc[4][4] = {};
  int am = tid >> 2, ak = (tid & 3) * 4;
  const float* arow = bcast ? (FT + (size_t)((m0 + am) & 63) * 256)
                            : (Fcur + (size_t)(m0 + am) * 256);
  int bk = tid >> 4, bn = (tid & 15) * 4;
  for (int k0 = 0; k0 < 256; k0 += 16) {
    float4 av = *(const float4*)(arow + k0 + ak);
    As[ak+0][am] = av.x; As[ak+1][am] = av.y; As[ak+2][am] = av.z; As[ak+3][am] = av.w;
    *(float4*)&Bs[bk][bn] = *(const float4*)(Bp + (size_t)(k0 + bk) * ldb + nb + bn);
    __syncthreads();
    #pragma unroll
    for (int kk = 0; kk < 16; ++kk) {
      float a0 = As[kk][ty*4+0], a1 = As[kk][ty*4+1], a2 = As[kk][ty*4+2], a3 = As[kk][ty*4+3];
      float b0 = Bs[kk][tx*4+0], b1 = Bs[kk][tx*4+1], b2 = Bs[kk][tx*4+2], b3 = Bs[kk][tx*4+3];
      acc[0][0]=fmaf(a0,b0,acc[0][0]); acc[0][1]=fmaf(a0,b1,acc[0][1]); acc[0][2]=fmaf(a0,b2,acc[0][2]); acc[0][3]=fmaf(a0,b3,acc[0][3]);
      acc[1][0]=fmaf(a1,b0,acc[1][0]); acc[1][1]=fmaf(a1,b1,acc[1][1]); acc[1][2]=fmaf(a1,b2,acc[1][2]); acc[1][3]=fmaf(a1,b3,acc[1][3]);
      acc[2][0]=fmaf(a2,b0,acc[2][0]); acc[2][1]=fmaf(a2,b1,acc[2][1]); acc[2][2]=fmaf(a2,b2,acc[2][2]); acc[2][3]=fmaf(a2,b3,acc[2][3]);
      acc[3][0]=fmaf(a3,b0,acc[3][0]); acc[3][1]=fmaf(a3,b1,acc[3][1]); acc[3][2]=fmaf(a3,b2,acc[3][2]); acc[3][3]=fmaf(a3,b3,acc[3][3]);
    }
    __syncthreads();
  }
  #pragma unroll
  for (int i = 0; i < 4; ++i) {
    float4 v = make_float4(acc[i][0], acc[i][1], acc[i][2], acc[i][3]);
    *(float4*)(U + (size_t)(m0 + ty*4 + i) * 1024 + n0 + tx*4) = v;
  }
}

// ---------- kernel 3 (per step): F_tilde GEMM2 + full gate epilogue -> Fnext ----------
// A[row,kk] = gelu(U1[row,kk] + rW1[b,kk] + b1[kk]); C = A @ mlp_W2; then gates.
__global__ __launch_bounds__(256) void gemm2_kernel(
    const float* __restrict__ U, const float* __restrict__ rW1, const float* __restrict__ b1,
    const float* __restrict__ W2, const float* __restrict__ b2,
    const float* __restrict__ Fcur, const float* __restrict__ FT, int bcast,
    const float* __restrict__ r, const float* __restrict__ rWf, const float* __restrict__ rWi,
    const float* __restrict__ bf, const float* __restrict__ bi,
    float* __restrict__ Fout)
{
  int bx = blockIdx.x & 3;    // 4 n-tiles of 64 over N=256
  int by = blockIdx.x >> 2;   // 256 m-tiles of 64 (one per batch b)
  int n0 = bx * 64, m0 = by * 64, bb = by;
  __shared__ float As[16][64];
  __shared__ float Bs[16][64];
  int tid = threadIdx.x, tx = tid & 15, ty = tid >> 4;
  float acc[4][4] = {};
  int am = tid >> 2, ak = (tid & 3) * 4;
  int bk = tid >> 4, bn = (tid & 15) * 4;
  const float* urow  = U + (size_t)(m0 + am) * 1024;
  const float* rwrow = rW1 + (size_t)bb * 512;
  for (int k0 = 0; k0 < 512; k0 += 16) {
    float4 uv = *(const float4*)(urow + k0 + ak);
    float4 rv = *(const float4*)(rwrow + k0 + ak);
    float4 bv = *(const float4*)(b1 + k0 + ak);
    As[ak+0][am] = gelu_f(uv.x + rv.x + bv.x);
    As[ak+1][am] = gelu_f(uv.y + rv.y + bv.y);
    As[ak+2][am] = gelu_f(uv.z + rv.z + bv.z);
    As[ak+3][am] = gelu_f(uv.w + rv.w + bv.w);
    *(float4*)&Bs[bk][bn] = *(const float4*)(W2 + (size_t)(k0 + bk) * 256 + n0 + bn);
    __syncthreads();
    #pragma unroll
    for (int kk = 0; kk < 16; ++kk) {
      float a0 = As[kk][ty*4+0], a1 = As[kk][ty*4+1], a2 = As[kk][ty*4+2], a3 = As[kk][ty*4+3];
      float b0_ = Bs[kk][tx*4+0], b1_ = Bs[kk][tx*4+1], b2_ = Bs[kk][tx*4+2], b3_ = Bs[kk][tx*4+3];
      acc[0][0]=fmaf(a0,b0_,acc[0][0]); acc[0][1]=fmaf(a0,b1_,acc[0][1]); acc[0][2]=fmaf(a0,b2_,acc[0][2]); acc[0][3]=fmaf(a0,b3_,acc[0][3]);
      acc[1][0]=fmaf(a1,b0_,acc[1][0]); acc[1][1]=fmaf(a1,b1_,acc[1][1]); acc[1][2]=fmaf(a1,b2_,acc[1][2]); acc[1][3]=fmaf(a1,b3_,acc[1][3]);
      acc[2][0]=fmaf(a2,b0_,acc[2][0]); acc[2][1]=fmaf(a2,b1_,acc[2][1]); acc[2][2]=fmaf(a2,b2_,acc[2][2]); acc[2][3]=fmaf(a2,b3_,acc[2][3]);
      acc[3][0]=fmaf(a3,b0_,acc[3][0]); acc[3][1]=fmaf(a3,b1_,acc[3][1]); acc[3][2]=fmaf(a3,b2_,acc[3][2]); acc[3][3]=fmaf(a3,b3_,acc[3][3]);
    }
    __syncthreads();
  }
  #pragma unroll
  for (int i = 0; i < 4; ++i) {
    int row = m0 + ty*4 + i;
    #pragma unroll
    for (int j = 0; j < 4; ++j) {
      int dcol = n0 + tx*4 + j;
      float Ftv = bcast ? FT[(size_t)(row & 63) * 256 + dcol]
                        : Fcur[(size_t)row * 256 + dcol];
      float rvv = r[(size_t)bb*256 + dcol];
      float xv = Ftv + rvv;
      float ftld = acc[i][j] + b2[dcol] + xv;
      float fg = sigmoid_f(rWf[(size_t)bb*256 + dcol] + bf[dcol] + tanhf(U[(size_t)row*1024 + 512 + dcol]));
      float ig = sigmoid_f(rWi[(size_t)bb*256 + dcol] + bi[dcol] + tanhf(U[(size_t)row*1024 + 768 + dcol]));
      Fout[(size_t)row*256 + dcol] = fg * Ftv + ig * tanhf(ftld);
    }
  }
}

// ---------- host ----------
extern "C" void kernel_launch(void* const* d_in, const int* in_sizes, int n_in,
                              void* d_out, int out_size, void* d_ws, size_t ws_size,
                              hipStream_t stream)
{
  (void)in_sizes; (void)n_in; (void)out_size; (void)ws_size;
  const float* wsi  = (const float*)d_in[0];
  const float* gen  = (const float*)d_in[1];
  const float* FT   = (const float*)d_in[2];
  const float* W_lr = (const float*)d_in[3];
  const float* b_lr = (const float*)d_in[4];
  const float* W_g  = (const float*)d_in[5];
  const float* b_g  = (const float*)d_in[6];
  const float* WqI  = (const float*)d_in[7];
  const float* WqG  = (const float*)d_in[8];
  const float* WkI  = (const float*)d_in[9];
  const float* WkG  = (const float*)d_in[10];
  const float* WvI  = (const float*)d_in[11];
  const float* WvG  = (const float*)d_in[12];
  const float* W1   = (const float*)d_in[13];
  const float* b1   = (const float*)d_in[14];
  const float* W2   = (const float*)d_in[15];
  const float* b2   = (const float*)d_in[16];
  const float* Wf   = (const float*)d_in[17];
  const float* bf   = (const float*)d_in[18];
  const float* Wi   = (const float*)d_in[19];
  const float* bi   = (const float*)d_in[20];
  const float* Vf   = (const float*)d_in[21];
  const float* Vi   = (const float*)d_in[22];
  const float* a_p  = (const float*)d_in[23];
  const float* b_p  = (const float*)d_in[24];

  float* out = (float*)d_out;
  float* ws  = (float*)d_ws;
  // workspace layout (floats): U | qIp | qGp | r | rW1 | rWf | rWi  (~69 MB)
  float* U   = ws;
  float* qIp = U   + (size_t)NROW * 1024;
  float* qGp = qIp + 65536;
  float* rr  = qGp + 65536;
  float* rW1 = rr  + 65536;
  float* rWf = rW1 + 131072;
  float* rWi = rWf + 65536;

  precompute_kernel<<<256, 256, 0, stream>>>(wsi, gen, W_lr, b_lr, W_g, b_g,
                                             WqI, WqG, WkI, WkG, a_p, b_p, qIp, qGp);

  // out[j] = F_{8-j}; step st (0-indexed) produces F_{st+1} -> slot 7-st.
  const float* Fcur = nullptr;
  int bcast = 1;
  for (int st = 0; st < T_; ++st) {
    float* Fnext = out + (size_t)(7 - st) * NROW * D_;
    step_attn_kernel<<<256, 256, 0, stream>>>(Fcur, FT, bcast, qIp, qGp, WvI, WvG,
                                              W1, Wf, Wi, a_p, b_p, rr, rW1, rWf, rWi);
    gemm1_kernel<<<4096, 256, 0, stream>>>(Fcur, FT, bcast, W1, Vf, Vi, U);
    gemm2_kernel<<<1024, 256, 0, stream>>>(U, rW1, b1, W2, b2, Fcur, FT, bcast,
                                           rr, rWf, rWi, bf, bi, Fnext);
    Fcur = Fnext;
    bcast = 0;
  }
}

// Round 3
// 2401.541 us; speedup vs baseline: 1.4568x; 1.4568x over previous
//
#include <hip/hip_runtime.h>

// Problem constants
#define B_    256
#define K_    64
#define D_    256
#define T_    8
#define NROW  (B_*K_)        // 16384 rows of the big GEMMs

// ---------- device helpers ----------
__device__ __forceinline__ float fexp2(float x) { return __builtin_amdgcn_exp2f(x); }
__device__ __forceinline__ float flog2(float x) { return __builtin_amdgcn_logf(x); }

__device__ __forceinline__ float sigmoid_f(float x) {
  return 1.f / (1.f + fexp2(x * -1.4426950408889634f));
}
__device__ __forceinline__ float tanh_fast(float x) {
  float xc = fminf(fmaxf(x, -30.f), 30.f);
  float t = fexp2(xc * 2.8853900817779268f);   // e^(2x)
  return (t - 1.f) / (t + 1.f);
}
__device__ __forceinline__ float gelu_f(float x) {
  return 0.5f * x * (1.f + erff(x * 0.70710678118654752440f));
}
// reference _mu_s with a2<b2 guaranteed by caller
__device__ __forceinline__ float muS_f(float x, float a2, float b2) {
  float mid = 0.5f * (a2 + b2);
  float inv = 1.f / (b2 - a2 + 1e-12f);
  if (x > b2)  return 1.f;
  if (x > mid) { float u = (b2 - x) * inv; return 1.f - 2.f * u * u; }
  if (x > a2)  { float u = (x - a2) * inv; return 2.f * u * u; }
  return 0.f;
}
// |z|^e2b via native log2/exp2 (z==0 -> log2=-inf -> exp2=0, correct)
__device__ __forceinline__ float pow_abs(float z, float e2b) {
  return fexp2(e2b * flog2(fabsf(z)));
}
// defuzzify one (rb, rs) pair -> 0.5*cen_b + 0.5*cen_s
__device__ __forceinline__ float defuzz_one(float rb_, float rs_, float ab, float bb) {
  float e2b = 2.f * bb;
  float inv_ab = 1.f / ab;
  float cb = 4.f * tanh_fast(rb_);
  float num = 0.f, den = 0.f;
  #pragma unroll
  for (int j = 0; j < 41; ++j) {
    float gj = -4.f + 0.2f * (float)j;
    float mu = 1.f / (1.f + pow_abs((gj - cb) * inv_ab, e2b));
    num += gj * mu; den += mu;
  }
  float cenb = num / (den + 1e-12f);
  float cs = 4.f * tanh_fast(rs_);
  float as_ = fminf(fmaxf(cs - 1.f, -4.f), 4.f);
  float bs_ = fminf(fmaxf(cs + 1.f, -4.f), 4.f);
  num = 0.f; den = 0.f;
  {
    float mid = 0.5f * (as_ + bs_);
    float inv = 1.f / (bs_ - as_ + 1e-12f);
    #pragma unroll
    for (int j = 0; j < 41; ++j) {
      float gj = -4.f + 0.2f * (float)j;
      float mu;
      if (gj > bs_)      mu = 1.f;
      else if (gj > mid) { float u = (bs_ - gj) * inv; mu = 1.f - 2.f * u * u; }
      else if (gj > as_) { float u = (gj - as_) * inv; mu = 2.f * u * u; }
      else               mu = 0.f;
      num += gj * mu; den += mu;
    }
  }
  float cens = num / (den + 1e-12f);
  return 0.5f * cenb + 0.5f * cens;
}

// ---------- kernel 0: one-time precompute ----------
__global__ __launch_bounds__(256) void precompute_kernel(
    const float* __restrict__ wsi, const float* __restrict__ gen,
    const float* __restrict__ W_lr, const float* __restrict__ b_lr,
    const float* __restrict__ W_g,  const float* __restrict__ b_g,
    const float* __restrict__ WqI,  const float* __restrict__ WqG,
    const float* __restrict__ WkI,  const float* __restrict__ WkG,
    const float* __restrict__ a_p,  const float* __restrict__ b_p,
    float* __restrict__ qIp, float* __restrict__ qGp)
{
  int b = blockIdx.x, t = threadIdx.x;
  __shared__ float xrow[1024];
  __shared__ float fz[512];
  __shared__ float Q[256];
  float ab = fmaxf(a_p[0], 0.001f), bb = fmaxf(b_p[0], 0.001f);
  float e2b = 2.f * bb, inv_ab = 1.f / ab;

  // ----- I path -----
  for (int i = t; i < 1024; i += 256) xrow[i] = wsi[(size_t)b*1024 + i];
  __syncthreads();
  float acc = b_lr[t];
  for (int e = 0; e < 1024; ++e) acc = fmaf(xrow[e], W_lr[(size_t)e*256 + t], acc);
  {
    float xs = 4.f * tanh_fast(acc * 0.25f);
    fz[t]       = 1.f / (1.f + pow_abs(xs * inv_ab, e2b));
    fz[256 + t] = muS_f(xs, -1.f, 1.f);
  }
  __syncthreads();
  float qi = 0.f;
  for (int e = 0; e < 512; ++e) qi = fmaf(fz[e], WqI[(size_t)e*256 + t], qi);
  Q[t] = qi;
  __syncthreads();
  float qp = 0.f;
  for (int dd = 0; dd < 256; ++dd) qp = fmaf(WkI[(size_t)t*256 + dd], Q[dd], qp);
  qIp[(size_t)b*256 + t] = qp;
  __syncthreads();

  // ----- G path -----
  for (int i = t; i < 512; i += 256) xrow[i] = gen[(size_t)b*512 + i];
  __syncthreads();
  acc = b_g[t];
  for (int e = 0; e < 512; ++e) acc = fmaf(xrow[e], W_g[(size_t)e*256 + t], acc);
  {
    float xs = 4.f * tanh_fast(acc * 0.25f);
    fz[t]       = 1.f / (1.f + pow_abs(xs * inv_ab, e2b));
    fz[256 + t] = muS_f(xs, -1.f, 1.f);
  }
  __syncthreads();
  qi = 0.f;
  for (int e = 0; e < 512; ++e) qi = fmaf(fz[e], WqG[(size_t)e*256 + t], qi);
  Q[t] = qi;
  __syncthreads();
  qp = 0.f;
  for (int dd = 0; dd < 256; ++dd) qp = fmaf(WkG[(size_t)t*256 + dd], Q[dd], qp);
  qGp[(size_t)b*256 + t] = qp;
}

// ---------- per step: scores + softmax + weighted sum  (one block per batch) ----------
__global__ __launch_bounds__(256) void k_ftbar(
    const float* __restrict__ Fcur, const float* __restrict__ FT, int bcast,
    const float* __restrict__ qIp, const float* __restrict__ qGp,
    float* __restrict__ ftbI, float* __restrict__ ftbG)
{
  int b = blockIdx.x, t = threadIdx.x;
  __shared__ float qv[2][256];
  __shared__ float red[2][256];
  __shared__ float p[2][64];
  const float* Fb = bcast ? FT : (Fcur + (size_t)b * K_ * D_);

  qv[0][t] = qIp[(size_t)b*256 + t];
  qv[1][t] = qGp[(size_t)b*256 + t];
  __syncthreads();

  // scores: sI[k] = Ft[b,k,:] . qIp[b,:] / 16 (4 partial lanes per k)
  {
    int k = t & 63, part = t >> 6;
    const float* frow = Fb + (size_t)k * D_ + part * 64;
    const float* q0 = &qv[0][part * 64];
    const float* q1 = &qv[1][part * 64];
    float s0 = 0.f, s1 = 0.f;
    for (int d = 0; d < 64; ++d) { float fv = frow[d]; s0 = fmaf(fv, q0[d], s0); s1 = fmaf(fv, q1[d], s1); }
    red[0][t] = s0; red[1][t] = s1;
  }
  __syncthreads();
  if (t < 128) {
    int which = t >> 6, kk = t & 63;
    float s = (red[which][kk] + red[which][64+kk] + red[which][128+kk] + red[which][192+kk]) * (1.f/16.f);
    float m = s;
    for (int off = 32; off; off >>= 1) m = fmaxf(m, __shfl_xor(m, off, 64));
    float e = fexp2((s - m) * 1.4426950408889634f);
    float sum = e;
    for (int off = 32; off; off >>= 1) sum += __shfl_xor(sum, off, 64);
    p[which][kk] = e / sum;
  }
  __syncthreads();
  // ftbar[d] = sum_k p[k] * Ft[b,k,d]   (coalesced)
  {
    float f0 = 0.f, f1 = 0.f;
    for (int kk = 0; kk < 64; ++kk) {
      float fv = Fb[(size_t)kk * D_ + t];
      f0 = fmaf(p[0][kk], fv, f0); f1 = fmaf(p[1][kk], fv, f1);
    }
    ftbI[(size_t)b*256 + t] = f0;
    ftbG[(size_t)b*256 + t] = f1;
  }
}

// ---------- per step: rt = [ftbI@WvI | ftbG@WvG]   M=256 N=1024 K=256 ----------
__global__ __launch_bounds__(256) void k_rt(
    const float* __restrict__ ftbI, const float* __restrict__ ftbG,
    const float* __restrict__ WvI,  const float* __restrict__ WvG,
    float* __restrict__ rt)
{
  int bx = blockIdx.x & 15, by = blockIdx.x >> 4;   // 16 n-tiles, 4 m-tiles
  int n0 = bx * 64, m0 = by * 64;
  const float* Ap = (n0 < 512) ? ftbI : ftbG;
  const float* Bp = (n0 < 512) ? WvI  : WvG;
  int nb = (n0 < 512) ? n0 : n0 - 512;
  __shared__ float As[16][64];
  __shared__ float Bs[16][64];
  int tid = threadIdx.x, tx = tid & 15, ty = tid >> 4;
  float acc[4][4] = {};
  int am = tid >> 2, ak = (tid & 3) * 4;
  int bk = tid >> 4, bn = (tid & 15) * 4;
  const float* arow = Ap + (size_t)(m0 + am) * 256;
  for (int k0 = 0; k0 < 256; k0 += 16) {
    float4 av = *(const float4*)(arow + k0 + ak);
    As[ak+0][am] = av.x; As[ak+1][am] = av.y; As[ak+2][am] = av.z; As[ak+3][am] = av.w;
    *(float4*)&Bs[bk][bn] = *(const float4*)(Bp + (size_t)(k0 + bk) * 512 + nb + bn);
    __syncthreads();
    #pragma unroll
    for (int kk = 0; kk < 16; ++kk) {
      float a0 = As[kk][ty*4+0], a1 = As[kk][ty*4+1], a2 = As[kk][ty*4+2], a3 = As[kk][ty*4+3];
      float b0 = Bs[kk][tx*4+0], b1 = Bs[kk][tx*4+1], b2 = Bs[kk][tx*4+2], b3 = Bs[kk][tx*4+3];
      acc[0][0]=fmaf(a0,b0,acc[0][0]); acc[0][1]=fmaf(a0,b1,acc[0][1]); acc[0][2]=fmaf(a0,b2,acc[0][2]); acc[0][3]=fmaf(a0,b3,acc[0][3]);
      acc[1][0]=fmaf(a1,b0,acc[1][0]); acc[1][1]=fmaf(a1,b1,acc[1][1]); acc[1][2]=fmaf(a1,b2,acc[1][2]); acc[1][3]=fmaf(a1,b3,acc[1][3]);
      acc[2][0]=fmaf(a2,b0,acc[2][0]); acc[2][1]=fmaf(a2,b1,acc[2][1]); acc[2][2]=fmaf(a2,b2,acc[2][2]); acc[2][3]=fmaf(a2,b3,acc[2][3]);
      acc[3][0]=fmaf(a3,b0,acc[3][0]); acc[3][1]=fmaf(a3,b1,acc[3][1]); acc[3][2]=fmaf(a3,b2,acc[3][2]); acc[3][3]=fmaf(a3,b3,acc[3][3]);
    }
    __syncthreads();
  }
  #pragma unroll
  for (int i = 0; i < 4; ++i) {
    float4 v = make_float4(acc[i][0], acc[i][1], acc[i][2], acc[i][3]);
    *(float4*)(rt + (size_t)(m0 + ty*4 + i) * 1024 + n0 + tx*4) = v;
  }
}

// ---------- per step: defuzzify -> r  (fully parallel) ----------
__global__ __launch_bounds__(256) void k_defuzz(
    const float* __restrict__ rt,
    const float* __restrict__ a_p, const float* __restrict__ b_p,
    float* __restrict__ r_out)
{
  int b = blockIdx.x, t = threadIdx.x;
  float ab = fmaxf(a_p[0], 0.001f), bb = fmaxf(b_p[0], 0.001f);
  const float* rb = rt + (size_t)b * 1024;
  float rI = defuzz_one(rb[t],       rb[256 + t], ab, bb);
  float rG = defuzz_one(rb[512 + t], rb[768 + t], ab, bb);
  r_out[(size_t)b*256 + t] = 0.5f * rI + 0.5f * rG;
}

// ---------- per step: rW = r @ [W1 | Wf | Wi]   M=256 N=1024 K=256 ----------
__global__ __launch_bounds__(256) void k_rW(
    const float* __restrict__ r,
    const float* __restrict__ W1, const float* __restrict__ Wf, const float* __restrict__ Wi,
    float* __restrict__ rW1, float* __restrict__ rWf, float* __restrict__ rWi)
{
  int bx = blockIdx.x & 15, by = blockIdx.x >> 4;
  int n0 = bx * 64, m0 = by * 64;
  const float* Bp; int ldb, nb;
  if (n0 < 512)      { Bp = W1; ldb = 512; nb = n0; }
  else if (n0 < 768) { Bp = Wf; ldb = 256; nb = n0 - 512; }
  else               { Bp = Wi; ldb = 256; nb = n0 - 768; }
  __shared__ float As[16][64];
  __shared__ float Bs[16][64];
  int tid = threadIdx.x, tx = tid & 15, ty = tid >> 4;
  float acc[4][4] = {};
  int am = tid >> 2, ak = (tid & 3) * 4;
  int bk = tid >> 4, bn = (tid & 15) * 4;
  const float* arow = r + (size_t)(m0 + am) * 256;
  for (int k0 = 0; k0 < 256; k0 += 16) {
    float4 av = *(const float4*)(arow + k0 + ak);
    As[ak+0][am] = av.x; As[ak+1][am] = av.y; As[ak+2][am] = av.z; As[ak+3][am] = av.w;
    *(float4*)&Bs[bk][bn] = *(const float4*)(Bp + (size_t)(k0 + bk) * ldb + nb + bn);
    __syncthreads();
    #pragma unroll
    for (int kk = 0; kk < 16; ++kk) {
      float a0 = As[kk][ty*4+0], a1 = As[kk][ty*4+1], a2 = As[kk][ty*4+2], a3 = As[kk][ty*4+3];
      float b0 = Bs[kk][tx*4+0], b1 = Bs[kk][tx*4+1], b2 = Bs[kk][tx*4+2], b3 = Bs[kk][tx*4+3];
      acc[0][0]=fmaf(a0,b0,acc[0][0]); acc[0][1]=fmaf(a0,b1,acc[0][1]); acc[0][2]=fmaf(a0,b2,acc[0][2]); acc[0][3]=fmaf(a0,b3,acc[0][3]);
      acc[1][0]=fmaf(a1,b0,acc[1][0]); acc[1][1]=fmaf(a1,b1,acc[1][1]); acc[1][2]=fmaf(a1,b2,acc[1][2]); acc[1][3]=fmaf(a1,b3,acc[1][3]);
      acc[2][0]=fmaf(a2,b0,acc[2][0]); acc[2][1]=fmaf(a2,b1,acc[2][1]); acc[2][2]=fmaf(a2,b2,acc[2][2]); acc[2][3]=fmaf(a2,b3,acc[2][3]);
      acc[3][0]=fmaf(a3,b0,acc[3][0]); acc[3][1]=fmaf(a3,b1,acc[3][1]); acc[3][2]=fmaf(a3,b2,acc[3][2]); acc[3][3]=fmaf(a3,b3,acc[3][3]);
    }
    __syncthreads();
  }
  #pragma unroll
  for (int i = 0; i < 4; ++i) {
    int row = m0 + ty*4 + i;
    float4 v = make_float4(acc[i][0], acc[i][1], acc[i][2], acc[i][3]);
    int c = tx * 4;
    if (n0 < 512)      *(float4*)(rW1 + (size_t)row*512 + n0 + c)        = v;
    else if (n0 < 768) *(float4*)(rWf + (size_t)row*256 + (n0-512) + c)  = v;
    else               *(float4*)(rWi + (size_t)row*256 + (n0-768) + c)  = v;
  }
}

// ---------- per step: U = Ft @ [mlp_W1 | Vf | Vi]  (16384x256 @ 256x1024) ----------
__global__ __launch_bounds__(256) void gemm1_kernel(
    const float* __restrict__ Fcur, const float* __restrict__ FT, int bcast,
    const float* __restrict__ W1, const float* __restrict__ Vf, const float* __restrict__ Vi,
    float* __restrict__ U)
{
  int bx = blockIdx.x & 15;
  int by = blockIdx.x >> 4;
  int n0 = bx * 64, m0 = by * 64;
  const float* Bp; int ldb, nb;
  if (n0 < 512)      { Bp = W1; ldb = 512; nb = n0; }
  else if (n0 < 768) { Bp = Vf; ldb = 256; nb = n0 - 512; }
  else               { Bp = Vi; ldb = 256; nb = n0 - 768; }
  __shared__ float As[16][64];
  __shared__ float Bs[16][64];
  int tid = threadIdx.x, tx = tid & 15, ty = tid >> 4;
  float acc[4][4] = {};
  int am = tid >> 2, ak = (tid & 3) * 4;
  const float* arow = bcast ? (FT + (size_t)((m0 + am) & 63) * 256)
                            : (Fcur + (size_t)(m0 + am) * 256);
  int bk = tid >> 4, bn = (tid & 15) * 4;
  for (int k0 = 0; k0 < 256; k0 += 16) {
    float4 av = *(const float4*)(arow + k0 + ak);
    As[ak+0][am] = av.x; As[ak+1][am] = av.y; As[ak+2][am] = av.z; As[ak+3][am] = av.w;
    *(float4*)&Bs[bk][bn] = *(const float4*)(Bp + (size_t)(k0 + bk) * ldb + nb + bn);
    __syncthreads();
    #pragma unroll
    for (int kk = 0; kk < 16; ++kk) {
      float a0 = As[kk][ty*4+0], a1 = As[kk][ty*4+1], a2 = As[kk][ty*4+2], a3 = As[kk][ty*4+3];
      float b0 = Bs[kk][tx*4+0], b1 = Bs[kk][tx*4+1], b2 = Bs[kk][tx*4+2], b3 = Bs[kk][tx*4+3];
      acc[0][0]=fmaf(a0,b0,acc[0][0]); acc[0][1]=fmaf(a0,b1,acc[0][1]); acc[0][2]=fmaf(a0,b2,acc[0][2]); acc[0][3]=fmaf(a0,b3,acc[0][3]);
      acc[1][0]=fmaf(a1,b0,acc[1][0]); acc[1][1]=fmaf(a1,b1,acc[1][1]); acc[1][2]=fmaf(a1,b2,acc[1][2]); acc[1][3]=fmaf(a1,b3,acc[1][3]);
      acc[2][0]=fmaf(a2,b0,acc[2][0]); acc[2][1]=fmaf(a2,b1,acc[2][1]); acc[2][2]=fmaf(a2,b2,acc[2][2]); acc[2][3]=fmaf(a2,b3,acc[2][3]);
      acc[3][0]=fmaf(a3,b0,acc[3][0]); acc[3][1]=fmaf(a3,b1,acc[3][1]); acc[3][2]=fmaf(a3,b2,acc[3][2]); acc[3][3]=fmaf(a3,b3,acc[3][3]);
    }
    __syncthreads();
  }
  #pragma unroll
  for (int i = 0; i < 4; ++i) {
    float4 v = make_float4(acc[i][0], acc[i][1], acc[i][2], acc[i][3]);
    *(float4*)(U + (size_t)(m0 + ty*4 + i) * 1024 + n0 + tx*4) = v;
  }
}

// ---------- per step: F_tilde GEMM2 + full gate epilogue -> Fnext ----------
__global__ __launch_bounds__(256) void gemm2_kernel(
    const float* __restrict__ U, const float* __restrict__ rW1, const float* __restrict__ b1,
    const float* __restrict__ W2, const float* __restrict__ b2,
    const float* __restrict__ Fcur, const float* __restrict__ FT, int bcast,
    const float* __restrict__ r, const float* __restrict__ rWf, const float* __restrict__ rWi,
    const float* __restrict__ bf, const float* __restrict__ bi,
    float* __restrict__ Fout)
{
  int bx = blockIdx.x & 3;
  int by = blockIdx.x >> 2;
  int n0 = bx * 64, m0 = by * 64, bb = by;
  __shared__ float As[16][64];
  __shared__ float Bs[16][64];
  int tid = threadIdx.x, tx = tid & 15, ty = tid >> 4;
  float acc[4][4] = {};
  int am = tid >> 2, ak = (tid & 3) * 4;
  int bk = tid >> 4, bn = (tid & 15) * 4;
  const float* urow  = U + (size_t)(m0 + am) * 1024;
  const float* rwrow = rW1 + (size_t)bb * 512;
  for (int k0 = 0; k0 < 512; k0 += 16) {
    float4 uv = *(const float4*)(urow + k0 + ak);
    float4 rv = *(const float4*)(rwrow + k0 + ak);
    float4 bv = *(const float4*)(b1 + k0 + ak);
    As[ak+0][am] = gelu_f(uv.x + rv.x + bv.x);
    As[ak+1][am] = gelu_f(uv.y + rv.y + bv.y);
    As[ak+2][am] = gelu_f(uv.z + rv.z + bv.z);
    As[ak+3][am] = gelu_f(uv.w + rv.w + bv.w);
    *(float4*)&Bs[bk][bn] = *(const float4*)(W2 + (size_t)(k0 + bk) * 256 + n0 + bn);
    __syncthreads();
    #pragma unroll
    for (int kk = 0; kk < 16; ++kk) {
      float a0 = As[kk][ty*4+0], a1 = As[kk][ty*4+1], a2 = As[kk][ty*4+2], a3 = As[kk][ty*4+3];
      float b0_ = Bs[kk][tx*4+0], b1_ = Bs[kk][tx*4+1], b2_ = Bs[kk][tx*4+2], b3_ = Bs[kk][tx*4+3];
      acc[0][0]=fmaf(a0,b0_,acc[0][0]); acc[0][1]=fmaf(a0,b1_,acc[0][1]); acc[0][2]=fmaf(a0,b2_,acc[0][2]); acc[0][3]=fmaf(a0,b3_,acc[0][3]);
      acc[1][0]=fmaf(a1,b0_,acc[1][0]); acc[1][1]=fmaf(a1,b1_,acc[1][1]); acc[1][2]=fmaf(a1,b2_,acc[1][2]); acc[1][3]=fmaf(a1,b3_,acc[1][3]);
      acc[2][0]=fmaf(a2,b0_,acc[2][0]); acc[2][1]=fmaf(a2,b1_,acc[2][1]); acc[2][2]=fmaf(a2,b2_,acc[2][2]); acc[2][3]=fmaf(a2,b3_,acc[2][3]);
      acc[3][0]=fmaf(a3,b0_,acc[3][0]); acc[3][1]=fmaf(a3,b1_,acc[3][1]); acc[3][2]=fmaf(a3,b2_,acc[3][2]); acc[3][3]=fmaf(a3,b3_,acc[3][3]);
    }
    __syncthreads();
  }
  #pragma unroll
  for (int i = 0; i < 4; ++i) {
    int row = m0 + ty*4 + i;
    #pragma unroll
    for (int j = 0; j < 4; ++j) {
      int dcol = n0 + tx*4 + j;
      float Ftv = bcast ? FT[(size_t)(row & 63) * 256 + dcol]
                        : Fcur[(size_t)row * 256 + dcol];
      float rvv = r[(size_t)bb*256 + dcol];
      float xv = Ftv + rvv;
      float ftld = acc[i][j] + b2[dcol] + xv;
      float fg = sigmoid_f(rWf[(size_t)bb*256 + dcol] + bf[dcol] + tanh_fast(U[(size_t)row*1024 + 512 + dcol]));
      float ig = sigmoid_f(rWi[(size_t)bb*256 + dcol] + bi[dcol] + tanh_fast(U[(size_t)row*1024 + 768 + dcol]));
      Fout[(size_t)row*256 + dcol] = fg * Ftv + ig * tanh_fast(ftld);
    }
  }
}

// ---------- host ----------
extern "C" void kernel_launch(void* const* d_in, const int* in_sizes, int n_in,
                              void* d_out, int out_size, void* d_ws, size_t ws_size,
                              hipStream_t stream)
{
  (void)in_sizes; (void)n_in; (void)out_size; (void)ws_size;
  const float* wsi  = (const float*)d_in[0];
  const float* gen  = (const float*)d_in[1];
  const float* FT   = (const float*)d_in[2];
  const float* W_lr = (const float*)d_in[3];
  const float* b_lr = (const float*)d_in[4];
  const float* W_g  = (const float*)d_in[5];
  const float* b_g  = (const float*)d_in[6];
  const float* WqI  = (const float*)d_in[7];
  const float* WqG  = (const float*)d_in[8];
  const float* WkI  = (const float*)d_in[9];
  const float* WkG  = (const float*)d_in[10];
  const float* WvI  = (const float*)d_in[11];
  const float* WvG  = (const float*)d_in[12];
  const float* W1   = (const float*)d_in[13];
  const float* b1   = (const float*)d_in[14];
  const float* W2   = (const float*)d_in[15];
  const float* b2   = (const float*)d_in[16];
  const float* Wf   = (const float*)d_in[17];
  const float* bf   = (const float*)d_in[18];
  const float* Wi   = (const float*)d_in[19];
  const float* bi   = (const float*)d_in[20];
  const float* Vf   = (const float*)d_in[21];
  const float* Vi   = (const float*)d_in[22];
  const float* a_p  = (const float*)d_in[23];
  const float* b_p  = (const float*)d_in[24];

  float* out = (float*)d_out;
  float* ws  = (float*)d_ws;
  // workspace layout (floats): U | qIp | qGp | ftbI | ftbG | rt | r | rW1 | rWf | rWi
  float* U    = ws;
  float* qIp  = U    + (size_t)NROW * 1024;
  float* qGp  = qIp  + 65536;
  float* ftbI = qGp  + 65536;
  float* ftbG = ftbI + 65536;
  float* rt   = ftbG + 65536;
  float* rr   = rt   + 262144;
  float* rW1  = rr   + 65536;
  float* rWf  = rW1  + 131072;
  float* rWi  = rWf  + 65536;

  precompute_kernel<<<256, 256, 0, stream>>>(wsi, gen, W_lr, b_lr, W_g, b_g,
                                             WqI, WqG, WkI, WkG, a_p, b_p, qIp, qGp);

  // out[j] = F_{8-j}; step st (0-indexed) produces F_{st+1} -> slot 7-st.
  const float* Fcur = nullptr;
  int bcast = 1;
  for (int st = 0; st < T_; ++st) {
    float* Fnext = out + (size_t)(7 - st) * NROW * D_;
    k_ftbar<<<256, 256, 0, stream>>>(Fcur, FT, bcast, qIp, qGp, ftbI, ftbG);
    k_rt<<<64, 256, 0, stream>>>(ftbI, ftbG, WvI, WvG, rt);
    k_defuzz<<<256, 256, 0, stream>>>(rt, a_p, b_p, rr);
    k_rW<<<64, 256, 0, stream>>>(rr, W1, Wf, Wi, rW1, rWf, rWi);
    gemm1_kernel<<<4096, 256, 0, stream>>>(Fcur, FT, bcast, W1, Vf, Vi, U);
    gemm2_kernel<<<1024, 256, 0, stream>>>(U, rW1, b1, W2, b2, Fcur, FT, bcast,
                                           rr, rWf, rWi, bf, bi, Fnext);
    Fcur = Fnext;
    bcast = 0;
  }
}

// Round 4
// 1507.736 us; speedup vs baseline: 2.3204x; 1.5928x over previous
//
#include <hip/hip_runtime.h>
#include <hip/hip_bf16.h>

// Problem constants
#define B_    256
#define K_    64
#define D_    256
#define T_    8
#define NROW  (B_*K_)        // 16384 rows of the big GEMMs

typedef short short8v __attribute__((ext_vector_type(8)));
typedef float f32x4  __attribute__((ext_vector_type(4)));

// ---------- device helpers ----------
__device__ __forceinline__ float fexp2(float x) { return __builtin_amdgcn_exp2f(x); }
__device__ __forceinline__ float flog2(float x) { return __builtin_amdgcn_logf(x); }

__device__ __forceinline__ float sigmoid_f(float x) {
  return 1.f / (1.f + fexp2(x * -1.4426950408889634f));
}
__device__ __forceinline__ float tanh_fast(float x) {
  float xc = fminf(fmaxf(x, -30.f), 30.f);
  float t = fexp2(xc * 2.8853900817779268f);   // e^(2x)
  return (t - 1.f) / (t + 1.f);
}
__device__ __forceinline__ float gelu_f(float x) {
  return 0.5f * x * (1.f + erff(x * 0.70710678118654752440f));
}
__device__ __forceinline__ unsigned short f2bf(float x) {
  __hip_bfloat16 h = __float2bfloat16(x);
  return *reinterpret_cast<unsigned short*>(&h);
}
// reference _mu_s with a2<b2 guaranteed by caller
__device__ __forceinline__ float muS_f(float x, float a2, float b2) {
  float mid = 0.5f * (a2 + b2);
  float inv = 1.f / (b2 - a2 + 1e-12f);
  if (x > b2)  return 1.f;
  if (x > mid) { float u = (b2 - x) * inv; return 1.f - 2.f * u * u; }
  if (x > a2)  { float u = (x - a2) * inv; return 2.f * u * u; }
  return 0.f;
}
__device__ __forceinline__ float pow_abs(float z, float e2b) {
  return fexp2(e2b * flog2(fabsf(z)));
}
__device__ __forceinline__ float defuzz_one(float rb_, float rs_, float ab, float bb) {
  float e2b = 2.f * bb;
  float inv_ab = 1.f / ab;
  float cb = 4.f * tanh_fast(rb_);
  float num = 0.f, den = 0.f;
  #pragma unroll
  for (int j = 0; j < 41; ++j) {
    float gj = -4.f + 0.2f * (float)j;
    float mu = 1.f / (1.f + pow_abs((gj - cb) * inv_ab, e2b));
    num += gj * mu; den += mu;
  }
  float cenb = num / (den + 1e-12f);
  float cs = 4.f * tanh_fast(rs_);
  float as_ = fminf(fmaxf(cs - 1.f, -4.f), 4.f);
  float bs_ = fminf(fmaxf(cs + 1.f, -4.f), 4.f);
  num = 0.f; den = 0.f;
  {
    float mid = 0.5f * (as_ + bs_);
    float inv = 1.f / (bs_ - as_ + 1e-12f);
    #pragma unroll
    for (int j = 0; j < 41; ++j) {
      float gj = -4.f + 0.2f * (float)j;
      float mu;
      if (gj > bs_)      mu = 1.f;
      else if (gj > mid) { float u = (bs_ - gj) * inv; mu = 1.f - 2.f * u * u; }
      else if (gj > as_) { float u = (gj - as_) * inv; mu = 2.f * u * u; }
      else               mu = 0.f;
      num += gj * mu; den += mu;
    }
  }
  float cens = num / (den + 1e-12f);
  return 0.5f * cenb + 0.5f * cens;
}

// ---------- one-time: weight transpose + bf16 conversion ----------
// B1t[n][k] (n<512: W1, <768: Vf, else Vi), W2t[n][k], FTbf (row-major copy)
__global__ __launch_bounds__(256) void k_convert(
    const float* __restrict__ W1, const float* __restrict__ Vf, const float* __restrict__ Vi,
    const float* __restrict__ W2, const float* __restrict__ FT,
    unsigned short* __restrict__ B1t, unsigned short* __restrict__ W2t,
    unsigned short* __restrict__ FTbf)
{
  int idx = blockIdx.x * 256 + threadIdx.x;
  if (idx < 262144) {
    int n = idx >> 8, k = idx & 255;
    float v = (n < 512) ? W1[(size_t)k*512 + n]
            : (n < 768) ? Vf[(size_t)k*256 + (n-512)]
                        : Vi[(size_t)k*256 + (n-768)];
    B1t[idx] = f2bf(v);
  } else if (idx < 262144 + 131072) {
    int j = idx - 262144;
    int n = j >> 9, k = j & 511;
    W2t[j] = f2bf(W2[(size_t)k*256 + n]);
  } else if (idx < 262144 + 131072 + 16384) {
    int j = idx - 393216;
    FTbf[j] = f2bf(FT[j]);
  }
}

// ---------- kernel 0: one-time precompute ----------
__global__ __launch_bounds__(256) void precompute_kernel(
    const float* __restrict__ wsi, const float* __restrict__ gen,
    const float* __restrict__ W_lr, const float* __restrict__ b_lr,
    const float* __restrict__ W_g,  const float* __restrict__ b_g,
    const float* __restrict__ WqI,  const float* __restrict__ WqG,
    const float* __restrict__ WkI,  const float* __restrict__ WkG,
    const float* __restrict__ a_p,  const float* __restrict__ b_p,
    float* __restrict__ qIp, float* __restrict__ qGp)
{
  int b = blockIdx.x, t = threadIdx.x;
  __shared__ float xrow[1024];
  __shared__ float fz[512];
  __shared__ float Q[256];
  float ab = fmaxf(a_p[0], 0.001f), bb = fmaxf(b_p[0], 0.001f);
  float e2b = 2.f * bb, inv_ab = 1.f / ab;

  for (int i = t; i < 1024; i += 256) xrow[i] = wsi[(size_t)b*1024 + i];
  __syncthreads();
  float acc = b_lr[t];
  for (int e = 0; e < 1024; ++e) acc = fmaf(xrow[e], W_lr[(size_t)e*256 + t], acc);
  {
    float xs = 4.f * tanh_fast(acc * 0.25f);
    fz[t]       = 1.f / (1.f + pow_abs(xs * inv_ab, e2b));
    fz[256 + t] = muS_f(xs, -1.f, 1.f);
  }
  __syncthreads();
  float qi = 0.f;
  for (int e = 0; e < 512; ++e) qi = fmaf(fz[e], WqI[(size_t)e*256 + t], qi);
  Q[t] = qi;
  __syncthreads();
  float qp = 0.f;
  for (int dd = 0; dd < 256; ++dd) qp = fmaf(WkI[(size_t)t*256 + dd], Q[dd], qp);
  qIp[(size_t)b*256 + t] = qp;
  __syncthreads();

  for (int i = t; i < 512; i += 256) xrow[i] = gen[(size_t)b*512 + i];
  __syncthreads();
  acc = b_g[t];
  for (int e = 0; e < 512; ++e) acc = fmaf(xrow[e], W_g[(size_t)e*256 + t], acc);
  {
    float xs = 4.f * tanh_fast(acc * 0.25f);
    fz[t]       = 1.f / (1.f + pow_abs(xs * inv_ab, e2b));
    fz[256 + t] = muS_f(xs, -1.f, 1.f);
  }
  __syncthreads();
  qi = 0.f;
  for (int e = 0; e < 512; ++e) qi = fmaf(fz[e], WqG[(size_t)e*256 + t], qi);
  Q[t] = qi;
  __syncthreads();
  qp = 0.f;
  for (int dd = 0; dd < 256; ++dd) qp = fmaf(WkG[(size_t)t*256 + dd], Q[dd], qp);
  qGp[(size_t)b*256 + t] = qp;
}

// ---------- per step: scores + softmax + weighted sum ----------
__global__ __launch_bounds__(256) void k_ftbar(
    const float* __restrict__ Fcur, const float* __restrict__ FT, int bcast,
    const float* __restrict__ qIp, const float* __restrict__ qGp,
    float* __restrict__ ftbI, float* __restrict__ ftbG)
{
  int b = blockIdx.x, t = threadIdx.x;
  __shared__ float qv[2][256];
  __shared__ float red[2][256];
  __shared__ float p[2][64];
  const float* Fb = bcast ? FT : (Fcur + (size_t)b * K_ * D_);

  qv[0][t] = qIp[(size_t)b*256 + t];
  qv[1][t] = qGp[(size_t)b*256 + t];
  __syncthreads();
  {
    int k = t & 63, part = t >> 6;
    const float* frow = Fb + (size_t)k * D_ + part * 64;
    const float* q0 = &qv[0][part * 64];
    const float* q1 = &qv[1][part * 64];
    float s0 = 0.f, s1 = 0.f;
    for (int d = 0; d < 64; ++d) { float fv = frow[d]; s0 = fmaf(fv, q0[d], s0); s1 = fmaf(fv, q1[d], s1); }
    red[0][t] = s0; red[1][t] = s1;
  }
  __syncthreads();
  if (t < 128) {
    int which = t >> 6, kk = t & 63;
    float s = (red[which][kk] + red[which][64+kk] + red[which][128+kk] + red[which][192+kk]) * (1.f/16.f);
    float m = s;
    for (int off = 32; off; off >>= 1) m = fmaxf(m, __shfl_xor(m, off, 64));
    float e = fexp2((s - m) * 1.4426950408889634f);
    float sum = e;
    for (int off = 32; off; off >>= 1) sum += __shfl_xor(sum, off, 64);
    p[which][kk] = e / sum;
  }
  __syncthreads();
  {
    float f0 = 0.f, f1 = 0.f;
    for (int kk = 0; kk < 64; ++kk) {
      float fv = Fb[(size_t)kk * D_ + t];
      f0 = fmaf(p[0][kk], fv, f0); f1 = fmaf(p[1][kk], fv, f1);
    }
    ftbI[(size_t)b*256 + t] = f0;
    ftbG[(size_t)b*256 + t] = f1;
  }
}

// ---------- per step: rt = [ftbI@WvI | ftbG@WvG]   M=256 N=1024 K=256 ----------
__global__ __launch_bounds__(256) void k_rt(
    const float* __restrict__ ftbI, const float* __restrict__ ftbG,
    const float* __restrict__ WvI,  const float* __restrict__ WvG,
    float* __restrict__ rt)
{
  int bx = blockIdx.x & 15, by = blockIdx.x >> 4;
  int n0 = bx * 64, m0 = by * 64;
  const float* Ap = (n0 < 512) ? ftbI : ftbG;
  const float* Bp = (n0 < 512) ? WvI  : WvG;
  int nb = (n0 < 512) ? n0 : n0 - 512;
  __shared__ float As[16][64];
  __shared__ float Bs[16][64];
  int tid = threadIdx.x, tx = tid & 15, ty = tid >> 4;
  float acc[4][4] = {};
  int am = tid >> 2, ak = (tid & 3) * 4;
  int bk = tid >> 4, bn = (tid & 15) * 4;
  const float* arow = Ap + (size_t)(m0 + am) * 256;
  for (int k0 = 0; k0 < 256; k0 += 16) {
    float4 av = *(const float4*)(arow + k0 + ak);
    As[ak+0][am] = av.x; As[ak+1][am] = av.y; As[ak+2][am] = av.z; As[ak+3][am] = av.w;
    *(float4*)&Bs[bk][bn] = *(const float4*)(Bp + (size_t)(k0 + bk) * 512 + nb + bn);
    __syncthreads();
    #pragma unroll
    for (int kk = 0; kk < 16; ++kk) {
      float a0 = As[kk][ty*4+0], a1 = As[kk][ty*4+1], a2 = As[kk][ty*4+2], a3 = As[kk][ty*4+3];
      float b0 = Bs[kk][tx*4+0], b1 = Bs[kk][tx*4+1], b2 = Bs[kk][tx*4+2], b3 = Bs[kk][tx*4+3];
      acc[0][0]=fmaf(a0,b0,acc[0][0]); acc[0][1]=fmaf(a0,b1,acc[0][1]); acc[0][2]=fmaf(a0,b2,acc[0][2]); acc[0][3]=fmaf(a0,b3,acc[0][3]);
      acc[1][0]=fmaf(a1,b0,acc[1][0]); acc[1][1]=fmaf(a1,b1,acc[1][1]); acc[1][2]=fmaf(a1,b2,acc[1][2]); acc[1][3]=fmaf(a1,b3,acc[1][3]);
      acc[2][0]=fmaf(a2,b0,acc[2][0]); acc[2][1]=fmaf(a2,b1,acc[2][1]); acc[2][2]=fmaf(a2,b2,acc[2][2]); acc[2][3]=fmaf(a2,b3,acc[2][3]);
      acc[3][0]=fmaf(a3,b0,acc[3][0]); acc[3][1]=fmaf(a3,b1,acc[3][1]); acc[3][2]=fmaf(a3,b2,acc[3][2]); acc[3][3]=fmaf(a3,b3,acc[3][3]);
    }
    __syncthreads();
  }
  #pragma unroll
  for (int i = 0; i < 4; ++i) {
    float4 v = make_float4(acc[i][0], acc[i][1], acc[i][2], acc[i][3]);
    *(float4*)(rt + (size_t)(m0 + ty*4 + i) * 1024 + n0 + tx*4) = v;
  }
}

// ---------- per step: defuzzify -> r ----------
__global__ __launch_bounds__(256) void k_defuzz(
    const float* __restrict__ rt,
    const float* __restrict__ a_p, const float* __restrict__ b_p,
    float* __restrict__ r_out)
{
  int b = blockIdx.x, t = threadIdx.x;
  float ab = fmaxf(a_p[0], 0.001f), bb = fmaxf(b_p[0], 0.001f);
  const float* rb = rt + (size_t)b * 1024;
  float rI = defuzz_one(rb[t],       rb[256 + t], ab, bb);
  float rG = defuzz_one(rb[512 + t], rb[768 + t], ab, bb);
  r_out[(size_t)b*256 + t] = 0.5f * rI + 0.5f * rG;
}

// ---------- per step: rW = r @ [W1 | Wf | Wi]   M=256 N=1024 K=256 ----------
__global__ __launch_bounds__(256) void k_rW(
    const float* __restrict__ r,
    const float* __restrict__ W1, const float* __restrict__ Wf, const float* __restrict__ Wi,
    float* __restrict__ rW1, float* __restrict__ rWf, float* __restrict__ rWi)
{
  int bx = blockIdx.x & 15, by = blockIdx.x >> 4;
  int n0 = bx * 64, m0 = by * 64;
  const float* Bp; int ldb, nb;
  if (n0 < 512)      { Bp = W1; ldb = 512; nb = n0; }
  else if (n0 < 768) { Bp = Wf; ldb = 256; nb = n0 - 512; }
  else               { Bp = Wi; ldb = 256; nb = n0 - 768; }
  __shared__ float As[16][64];
  __shared__ float Bs[16][64];
  int tid = threadIdx.x, tx = tid & 15, ty = tid >> 4;
  float acc[4][4] = {};
  int am = tid >> 2, ak = (tid & 3) * 4;
  int bk = tid >> 4, bn = (tid & 15) * 4;
  const float* arow = r + (size_t)(m0 + am) * 256;
  for (int k0 = 0; k0 < 256; k0 += 16) {
    float4 av = *(const float4*)(arow + k0 + ak);
    As[ak+0][am] = av.x; As[ak+1][am] = av.y; As[ak+2][am] = av.z; As[ak+3][am] = av.w;
    *(float4*)&Bs[bk][bn] = *(const float4*)(Bp + (size_t)(k0 + bk) * ldb + nb + bn);
    __syncthreads();
    #pragma unroll
    for (int kk = 0; kk < 16; ++kk) {
      float a0 = As[kk][ty*4+0], a1 = As[kk][ty*4+1], a2 = As[kk][ty*4+2], a3 = As[kk][ty*4+3];
      float b0 = Bs[kk][tx*4+0], b1 = Bs[kk][tx*4+1], b2 = Bs[kk][tx*4+2], b3 = Bs[kk][tx*4+3];
      acc[0][0]=fmaf(a0,b0,acc[0][0]); acc[0][1]=fmaf(a0,b1,acc[0][1]); acc[0][2]=fmaf(a0,b2,acc[0][2]); acc[0][3]=fmaf(a0,b3,acc[0][3]);
      acc[1][0]=fmaf(a1,b0,acc[1][0]); acc[1][1]=fmaf(a1,b1,acc[1][1]); acc[1][2]=fmaf(a1,b2,acc[1][2]); acc[1][3]=fmaf(a1,b3,acc[1][3]);
      acc[2][0]=fmaf(a2,b0,acc[2][0]); acc[2][1]=fmaf(a2,b1,acc[2][1]); acc[2][2]=fmaf(a2,b2,acc[2][2]); acc[2][3]=fmaf(a2,b3,acc[2][3]);
      acc[3][0]=fmaf(a3,b0,acc[3][0]); acc[3][1]=fmaf(a3,b1,acc[3][1]); acc[3][2]=fmaf(a3,b2,acc[3][2]); acc[3][3]=fmaf(a3,b3,acc[3][3]);
    }
    __syncthreads();
  }
  #pragma unroll
  for (int i = 0; i < 4; ++i) {
    int row = m0 + ty*4 + i;
    float4 v = make_float4(acc[i][0], acc[i][1], acc[i][2], acc[i][3]);
    int c = tx * 4;
    if (n0 < 512)      *(float4*)(rW1 + (size_t)row*512 + n0 + c)        = v;
    else if (n0 < 768) *(float4*)(rWf + (size_t)row*256 + (n0-512) + c)  = v;
    else               *(float4*)(rWi + (size_t)row*256 + (n0-768) + c)  = v;
  }
}

// ---------- per step: MFMA GEMM1: [16384,256]bf16 @ B1t^T -> epilogues ----------
// n-tiles 0-3: A2 = bf16(gelu(u + rW1 + b1)); tiles 4-5: fg = sigmoid(rWf+bf+tanh(u));
// tiles 6-7: ig = sigmoid(rWi+bi+tanh(u))
__global__ __launch_bounds__(256) void mfma_gemm1(
    const unsigned short* __restrict__ Abf, int bcast,
    const unsigned short* __restrict__ B1t,
    const float* __restrict__ rW1, const float* __restrict__ b1,
    const float* __restrict__ rWf, const float* __restrict__ bfv,
    const float* __restrict__ rWi, const float* __restrict__ biv,
    unsigned short* __restrict__ A2, float* __restrict__ fgbuf, float* __restrict__ igbuf)
{
  int bx = blockIdx.x & 7, by = blockIdx.x >> 3;
  int n0 = bx * 128, m0 = by * 128;
  __shared__ short As[128][72];
  __shared__ short Bs[128][72];
  int tid = threadIdx.x;
  int w = tid >> 6, wm = w >> 1, wn = w & 1, lane = tid & 63, lr = lane & 15, lh = lane >> 4;
  f32x4 acc[4][4] = {};

  int srow = tid >> 3, koff = (tid & 7) * 8;
  for (int k0 = 0; k0 < 256; k0 += 64) {
    #pragma unroll
    for (int rnd = 0; rnd < 4; ++rnd) {
      int rrow = rnd * 32 + srow;
      int ar = bcast ? ((m0 + rrow) & 63) : (m0 + rrow);
      *(float4*)&As[rrow][koff] = *(const float4*)(Abf + (size_t)ar * 256 + k0 + koff);
      *(float4*)&Bs[rrow][koff] = *(const float4*)(B1t + (size_t)(n0 + rrow) * 256 + k0 + koff);
    }
    __syncthreads();
    #pragma unroll
    for (int ks = 0; ks < 2; ++ks) {
      short8v a[4], b[4];
      #pragma unroll
      for (int m = 0; m < 4; ++m) a[m] = *(const short8v*)&As[wm*64 + m*16 + lr][ks*32 + lh*8];
      #pragma unroll
      for (int n = 0; n < 4; ++n) b[n] = *(const short8v*)&Bs[wn*64 + n*16 + lr][ks*32 + lh*8];
      #pragma unroll
      for (int m = 0; m < 4; ++m)
        #pragma unroll
        for (int n = 0; n < 4; ++n)
          acc[m][n] = __builtin_amdgcn_mfma_f32_16x16x32_bf16(a[m], b[n], acc[m][n], 0, 0, 0);
    }
    __syncthreads();
  }

  int b_ix = (m0 >> 6) + wm;
  if (bx < 4) {
    const float* rwp = rW1 + (size_t)b_ix * 512;
    #pragma unroll
    for (int n = 0; n < 4; ++n) {
      int col = n0 + wn*64 + n*16 + lr;
      float add = rwp[col] + b1[col];
      #pragma unroll
      for (int m = 0; m < 4; ++m) {
        int rbase = m0 + wm*64 + m*16 + lh*4;
        #pragma unroll
        for (int r = 0; r < 4; ++r) {
          float v = acc[m][n][r] + add;
          A2[(size_t)(rbase + r) * 512 + col] = f2bf(gelu_f(v));
        }
      }
    }
  } else {
    int isI = (bx >= 6);
    const float* rwp = (isI ? rWi : rWf) + (size_t)b_ix * 256;
    const float* bp  = isI ? biv : bfv;
    float* outp      = isI ? igbuf : fgbuf;
    int cbase = isI ? 768 : 512;
    #pragma unroll
    for (int n = 0; n < 4; ++n) {
      int col = n0 + wn*64 + n*16 + lr;
      int c = col - cbase;
      float add = rwp[c] + bp[c];
      #pragma unroll
      for (int m = 0; m < 4; ++m) {
        int rbase = m0 + wm*64 + m*16 + lh*4;
        #pragma unroll
        for (int r = 0; r < 4; ++r)
          outp[(size_t)(rbase + r) * 256 + c] = sigmoid_f(add + tanh_fast(acc[m][n][r]));
      }
    }
  }
}

// ---------- per step: MFMA GEMM2: A2[16384,512]bf16 @ W2t^T + gate epilogue ----------
__global__ __launch_bounds__(256) void mfma_gemm2(
    const unsigned short* __restrict__ A2, const unsigned short* __restrict__ W2t,
    const float* __restrict__ b2,
    const float* __restrict__ Fprev, const float* __restrict__ FT, int bcast,
    const float* __restrict__ rr,
    const float* __restrict__ fgbuf, const float* __restrict__ igbuf,
    float* __restrict__ Fout, unsigned short* __restrict__ Fbf)
{
  int bx = blockIdx.x & 1, by = blockIdx.x >> 1;
  int n0 = bx * 128, m0 = by * 128;
  __shared__ short As[128][72];
  __shared__ short Bs[128][72];
  int tid = threadIdx.x;
  int w = tid >> 6, wm = w >> 1, wn = w & 1, lane = tid & 63, lr = lane & 15, lh = lane >> 4;
  f32x4 acc[4][4] = {};

  int srow = tid >> 3, koff = (tid & 7) * 8;
  for (int k0 = 0; k0 < 512; k0 += 64) {
    #pragma unroll
    for (int rnd = 0; rnd < 4; ++rnd) {
      int rrow = rnd * 32 + srow;
      *(float4*)&As[rrow][koff] = *(const float4*)(A2  + (size_t)(m0 + rrow) * 512 + k0 + koff);
      *(float4*)&Bs[rrow][koff] = *(const float4*)(W2t + (size_t)(n0 + rrow) * 512 + k0 + koff);
    }
    __syncthreads();
    #pragma unroll
    for (int ks = 0; ks < 2; ++ks) {
      short8v a[4], b[4];
      #pragma unroll
      for (int m = 0; m < 4; ++m) a[m] = *(const short8v*)&As[wm*64 + m*16 + lr][ks*32 + lh*8];
      #pragma unroll
      for (int n = 0; n < 4; ++n) b[n] = *(const short8v*)&Bs[wn*64 + n*16 + lr][ks*32 + lh*8];
      #pragma unroll
      for (int m = 0; m < 4; ++m)
        #pragma unroll
        for (int n = 0; n < 4; ++n)
          acc[m][n] = __builtin_amdgcn_mfma_f32_16x16x32_bf16(a[m], b[n], acc[m][n], 0, 0, 0);
    }
    __syncthreads();
  }

  int b_ix = (m0 >> 6) + wm;
  const float* rp = rr + (size_t)b_ix * 256;
  #pragma unroll
  for (int n = 0; n < 4; ++n) {
    int col = n0 + wn*64 + n*16 + lr;
    float b2c = b2[col], rv = rp[col];
    #pragma unroll
    for (int m = 0; m < 4; ++m) {
      int rbase = m0 + wm*64 + m*16 + lh*4;
      #pragma unroll
      for (int r = 0; r < 4; ++r) {
        int row = rbase + r;
        float Ftv = bcast ? FT[(size_t)(row & 63) * 256 + col]
                          : Fprev[(size_t)row * 256 + col];
        float ftld = acc[m][n][r] + b2c + Ftv + rv;
        float ov = fgbuf[(size_t)row * 256 + col] * Ftv
                 + igbuf[(size_t)row * 256 + col] * tanh_fast(ftld);
        Fout[(size_t)row * 256 + col] = ov;
        Fbf[(size_t)row * 256 + col] = f2bf(ov);
      }
    }
  }
}

// ---------- host ----------
extern "C" void kernel_launch(void* const* d_in, const int* in_sizes, int n_in,
                              void* d_out, int out_size, void* d_ws, size_t ws_size,
                              hipStream_t stream)
{
  (void)in_sizes; (void)n_in; (void)out_size; (void)ws_size;
  const float* wsi  = (const float*)d_in[0];
  const float* gen  = (const float*)d_in[1];
  const float* FT   = (const float*)d_in[2];
  const float* W_lr = (const float*)d_in[3];
  const float* b_lr = (const float*)d_in[4];
  const float* W_g  = (const float*)d_in[5];
  const float* b_g  = (const float*)d_in[6];
  const float* WqI  = (const float*)d_in[7];
  const float* WqG  = (const float*)d_in[8];
  const float* WkI  = (const float*)d_in[9];
  const float* WkG  = (const float*)d_in[10];
  const float* WvI  = (const float*)d_in[11];
  const float* WvG  = (const float*)d_in[12];
  const float* W1   = (const float*)d_in[13];
  const float* b1   = (const float*)d_in[14];
  const float* W2   = (const float*)d_in[15];
  const float* b2   = (const float*)d_in[16];
  const float* Wf   = (const float*)d_in[17];
  const float* bf   = (const float*)d_in[18];
  const float* Wi   = (const float*)d_in[19];
  const float* bi   = (const float*)d_in[20];
  const float* Vf   = (const float*)d_in[21];
  const float* Vi   = (const float*)d_in[22];
  const float* a_p  = (const float*)d_in[23];
  const float* b_p  = (const float*)d_in[24];

  float* out = (float*)d_out;
  float* ws  = (float*)d_ws;
  // fp32 region
  float* fgbuf = ws;                    // 16384*256
  float* igbuf = fgbuf + 4194304;       // 16384*256
  float* rt    = igbuf + 4194304;       // 256*1024
  float* rr    = rt    + 262144;        // 256*256
  float* rW1   = rr    + 65536;         // 256*512
  float* rWf   = rW1   + 131072;        // 256*256
  float* rWi   = rWf   + 65536;         // 256*256
  float* qIp   = rWi   + 65536;
  float* qGp   = qIp   + 65536;
  float* ftbI  = qGp   + 65536;
  float* ftbG  = ftbI  + 65536;
  // bf16 region
  unsigned short* A2   = (unsigned short*)(ftbG + 65536);  // 16384*512
  unsigned short* Fbf  = A2   + 8388608;                   // 16384*256
  unsigned short* FTbf = Fbf  + 4194304;                   // 64*256
  unsigned short* B1t  = FTbf + 16384;                     // 1024*256
  unsigned short* W2t  = B1t  + 262144;                    // 256*512

  precompute_kernel<<<256, 256, 0, stream>>>(wsi, gen, W_lr, b_lr, W_g, b_g,
                                             WqI, WqG, WkI, WkG, a_p, b_p, qIp, qGp);
  k_convert<<<1600, 256, 0, stream>>>(W1, Vf, Vi, W2, FT, B1t, W2t, FTbf);

  // out[j] = F_{8-j}; step st produces F_{st+1} -> slot 7-st.
  const float* Fcur = nullptr;
  int bcast = 1;
  for (int st = 0; st < T_; ++st) {
    float* Fnext = out + (size_t)(7 - st) * NROW * D_;
    k_ftbar<<<256, 256, 0, stream>>>(Fcur, FT, bcast, qIp, qGp, ftbI, ftbG);
    k_rt<<<64, 256, 0, stream>>>(ftbI, ftbG, WvI, WvG, rt);
    k_defuzz<<<256, 256, 0, stream>>>(rt, a_p, b_p, rr);
    k_rW<<<64, 256, 0, stream>>>(rr, W1, Wf, Wi, rW1, rWf, rWi);
    mfma_gemm1<<<1024, 256, 0, stream>>>(bcast ? FTbf : Fbf, bcast, B1t,
                                         rW1, b1, rWf, bf, rWi, bi,
                                         A2, fgbuf, igbuf);
    mfma_gemm2<<<256, 256, 0, stream>>>(A2, W2t, b2, Fcur, FT, bcast, rr,
                                        fgbuf, igbuf, Fnext, Fbf);
    Fcur = Fnext;
    bcast = 0;
  }
}